// Round 1
// baseline (453.717 us; speedup 1.0000x reference)
//
#include <hip/hip_runtime.h>
#include <stdint.h>

// CommNetActor: B=8192, A=64 agents, OBS=128, D=64, NACT=32
// Inputs: O, W_enc, b_enc, W1,b1, W2,b2, W3,b3, W4,b4, W_dec, b_dec (all fp32)
//
// Math folding: comm layer  H' = Hcat @ W + b,  Hcat=[H_i, (S-H_i)/64]
//   = H_i @ (Wtop - Wbot/64) + (S/64) @ Wbot + b
//   = [H_i | S/64] @ [Wtop - Wbot/64 ; Wbot] + b     (K=128 MFMA, bias in acc init)

#define BATCHN 8192
#define NAGENT 64
#define OBSD   128
#define DD     64
#define NACT   32

typedef __attribute__((ext_vector_type(8))) short short8;   // 8 bf16 (4 VGPRs)
typedef __attribute__((ext_vector_type(4))) float floatx4;  // MFMA acc

__device__ __forceinline__ unsigned short f2b(float f) {
    // fp32 -> bf16 round-to-nearest-even
    union { float f; uint32_t u; } v; v.f = f;
    uint32_t r = v.u + 0x7FFFu + ((v.u >> 16) & 1u);
    return (unsigned short)(r >> 16);
}

// ---- ws layout (byte offsets; ws treated as ushort*) ----
#define OFF_WENC 0                       // WencT  [64 n][128 k] bf16 = 16384 B
#define OFF_WCAT 16384                   // WcatT  [4 l][64 n][128 k] bf16 = 65536 B
#define OFF_WDEC 81920                   // WdecT  [32 n][4096 k] bf16 = 262144 B
#define OFF_H4   344064                  // H4     [8192][4096] bf16 = 67108864 B

// ---------------- prep: transpose + bf16-convert weights ----------------
__global__ __launch_bounds__(256) void prep_kernel(
    const float* __restrict__ Wenc,
    const float* __restrict__ W1, const float* __restrict__ W2,
    const float* __restrict__ W3, const float* __restrict__ W4,
    const float* __restrict__ Wdec,
    unsigned short* __restrict__ ws)
{
    int tid = blockIdx.x * 256 + threadIdx.x;   // grid covers exactly 172032
    if (tid < 8192) {
        int n = tid >> 7, k = tid & 127;
        ws[OFF_WENC/2 + n*128 + k] = f2b(Wenc[k*64 + n]);
    } else if (tid < 5*8192) {
        int l = (tid - 8192) >> 13;
        int e = (tid - 8192) & 8191;
        int n = e >> 7, k = e & 127;
        const float* W = (l==0) ? W1 : (l==1) ? W2 : (l==2) ? W3 : W4;
        float v = W[k*64 + n];                       // k<64: Wtop[k][n], k>=64: Wbot[k-64][n]
        if (k < 64) v -= W[(k+64)*64 + n] * (1.0f/64.0f);
        ws[OFF_WCAT/2 + l*8192 + n*128 + k] = f2b(v);
    } else {
        int e = tid - 5*8192;                        // 0..131071
        int n = e >> 12, k = e & 4095;
        ws[OFF_WDEC/2 + n*4096 + k] = f2b(Wdec[k*32 + n]);
    }
}

// ---------------- fused encoder + 4 comm layers ----------------
// 1 block = 1 sample. 256 thr = 4 waves, wave w owns rows [16w,16w+16).
__global__ __launch_bounds__(256) void fused_kernel(
    const float* __restrict__ O,
    const unsigned short* __restrict__ WencT,
    const unsigned short* __restrict__ WcatT,
    const float* __restrict__ b_enc,
    const float* __restrict__ b1, const float* __restrict__ b2,
    const float* __restrict__ b3, const float* __restrict__ b4,
    unsigned short* __restrict__ H4out)
{
    __shared__ __align__(16) unsigned short sA[64*136];   // O tile bf16, pad 8
    __shared__ __align__(16) unsigned short sW[64*136];   // current B^T, pad 8
    __shared__ __align__(16) unsigned short sH[64*72];    // H (64x64), pad 8
    __shared__ __align__(16) unsigned short sS[64];       // S/64 bf16
    __shared__ float sPart[4][64];                        // per-wave column partials

    const int t = threadIdx.x;
    const int b = blockIdx.x;
    const int lane = t & 63;
    const int w = t >> 6;
    const int m = lane & 15;
    const int q = lane >> 4;

    // stage O[b] fp32->bf16 (coalesced float4) and WencT
    {
        const float* Ob = O + (size_t)b * (NAGENT*OBSD);
        #pragma unroll
        for (int i = 0; i < 8; i++) {
            int e = t*4 + i*1024;
            float4 f = *(const float4*)(Ob + e);
            int row = e >> 7, col = e & 127;
            uint2 pk;
            pk.x = (uint32_t)f2b(f.x) | ((uint32_t)f2b(f.y) << 16);
            pk.y = (uint32_t)f2b(f.z) | ((uint32_t)f2b(f.w) << 16);
            *(uint2*)&sA[row*136 + col] = pk;
        }
        #pragma unroll
        for (int i = 0; i < 4; i++) {
            int c = t + i*256;                 // 1024 chunks x 8 ushort
            int e = c*8;
            int row = e >> 7, col = e & 127;
            *(uint4*)&sW[row*136 + col] = *(const uint4*)(WencT + e);
        }
    }
    __syncthreads();

    floatx4 acc[4];

    // ---- encoder: H0 = sigmoid(O @ Wenc + b_enc), K=128 ----
    #pragma unroll
    for (int nt = 0; nt < 4; nt++) {
        float bias = b_enc[nt*16 + m];
        acc[nt] = (floatx4){bias, bias, bias, bias};
    }
    #pragma unroll
    for (int s = 0; s < 4; s++) {
        short8 a = *(const short8*)&sA[(w*16 + m)*136 + s*32 + q*8];
        #pragma unroll
        for (int nt = 0; nt < 4; nt++) {
            short8 bb = *(const short8*)&sW[(nt*16 + m)*136 + s*32 + q*8];
            acc[nt] = __builtin_amdgcn_mfma_f32_16x16x32_bf16(a, bb, acc[nt], 0, 0, 0);
        }
    }
    #pragma unroll
    for (int nt = 0; nt < 4; nt++)
        #pragma unroll
        for (int r = 0; r < 4; r++)
            acc[nt][r] = 1.0f / (1.0f + __expf(-acc[nt][r]));

    // encoder epilogue: column sums (for S) + store H0 bf16
    #pragma unroll
    for (int nt = 0; nt < 4; nt++) {
        float s = acc[nt][0] + acc[nt][1] + acc[nt][2] + acc[nt][3];
        s += __shfl_xor(s, 16, 64);
        s += __shfl_xor(s, 32, 64);
        if (q == 0) sPart[w][nt*16 + m] = s;
        #pragma unroll
        for (int r = 0; r < 4; r++)
            sH[(w*16 + q*4 + r)*72 + nt*16 + m] = f2b(acc[nt][r]);
    }

    // ---- 4 comm layers ----
    const float* bs[4] = {b1, b2, b3, b4};
    #pragma unroll
    for (int l = 0; l < 4; l++) {
        __syncthreads();   // old sW reads done; sPart writes visible
        #pragma unroll
        for (int i = 0; i < 4; i++) {
            int c = t + i*256;
            int e = c*8;
            int row = e >> 7, col = e & 127;
            *(uint4*)&sW[row*136 + col] = *(const uint4*)(WcatT + l*8192 + e);
        }
        if (t < 64)
            sS[t] = f2b((sPart[0][t] + sPart[1][t] + sPart[2][t] + sPart[3][t]) * (1.0f/64.0f));
        __syncthreads();

        const float* bl = bs[l];
        #pragma unroll
        for (int nt = 0; nt < 4; nt++) {
            float bias = bl[nt*16 + m];
            acc[nt] = (floatx4){bias, bias, bias, bias};
        }
        // k = 0..63 from H rows
        #pragma unroll
        for (int s = 0; s < 2; s++) {
            short8 a = *(const short8*)&sH[(w*16 + m)*72 + s*32 + q*8];
            #pragma unroll
            for (int nt = 0; nt < 4; nt++) {
                short8 bb = *(const short8*)&sW[(nt*16 + m)*136 + s*32 + q*8];
                acc[nt] = __builtin_amdgcn_mfma_f32_16x16x32_bf16(a, bb, acc[nt], 0, 0, 0);
            }
        }
        // k = 64..127: A rows are all S/64 (LDS broadcast)
        #pragma unroll
        for (int s = 0; s < 2; s++) {
            short8 a = *(const short8*)&sS[s*32 + q*8];
            #pragma unroll
            for (int nt = 0; nt < 4; nt++) {
                short8 bb = *(const short8*)&sW[(nt*16 + m)*136 + (s+2)*32 + q*8];
                acc[nt] = __builtin_amdgcn_mfma_f32_16x16x32_bf16(a, bb, acc[nt], 0, 0, 0);
            }
        }

        if (l < 3) {
            #pragma unroll
            for (int nt = 0; nt < 4; nt++) {
                float s = acc[nt][0] + acc[nt][1] + acc[nt][2] + acc[nt][3];
                s += __shfl_xor(s, 16, 64);
                s += __shfl_xor(s, 32, 64);
                if (q == 0) sPart[w][nt*16 + m] = s;
                #pragma unroll
                for (int r = 0; r < 4; r++)
                    sH[(w*16 + q*4 + r)*72 + nt*16 + m] = f2b(acc[nt][r]);
            }
        } else {
            unsigned short* Hb = H4out + (size_t)b * 4096;
            #pragma unroll
            for (int nt = 0; nt < 4; nt++)
                #pragma unroll
                for (int r = 0; r < 4; r++)
                    Hb[(w*16 + q*4 + r)*64 + nt*16 + m] = f2b(acc[nt][r]);
        }
    }
}

// ---------------- decoder: out = Hf @ Wdec + b_dec ----------------
// M=8192, N=32, K=4096; K-split x8, fp32 atomicAdd epilogue (out pre-zeroed).
__global__ __launch_bounds__(256) void dec_kernel(
    const unsigned short* __restrict__ Hf,     // [8192][4096] bf16
    const unsigned short* __restrict__ WdecT,  // [32][4096] bf16
    const float* __restrict__ b_dec,
    float* __restrict__ out)                   // [8192][32] fp32
{
    int gt = blockIdx.x * 256 + threadIdx.x;
    int wave = gt >> 6;          // 0..4095
    int lane = gt & 63;
    int rb = wave >> 3;          // row block: rows [rb*16, rb*16+16)
    int kc = wave & 7;           // K chunk: [kc*512, kc*512+512)
    int m = lane & 15, q = lane >> 4;

    const unsigned short* aP  = Hf    + (size_t)(rb*16 + m)*4096 + kc*512 + q*8;
    const unsigned short* bP0 = WdecT + (size_t)m*4096        + kc*512 + q*8;
    const unsigned short* bP1 = WdecT + (size_t)(16 + m)*4096 + kc*512 + q*8;

    floatx4 a0 = {0.f, 0.f, 0.f, 0.f}, a1 = {0.f, 0.f, 0.f, 0.f};
    #pragma unroll 4
    for (int s = 0; s < 16; s++) {
        short8 av  = *(const short8*)(aP  + s*32);
        short8 b0v = *(const short8*)(bP0 + s*32);
        short8 b1v = *(const short8*)(bP1 + s*32);
        a0 = __builtin_amdgcn_mfma_f32_16x16x32_bf16(av, b0v, a0, 0, 0, 0);
        a1 = __builtin_amdgcn_mfma_f32_16x16x32_bf16(av, b1v, a1, 0, 0, 0);
    }
    float bias0 = (kc == 0) ? b_dec[m]      : 0.0f;
    float bias1 = (kc == 0) ? b_dec[16 + m] : 0.0f;
    #pragma unroll
    for (int r = 0; r < 4; r++) {
        int row = rb*16 + q*4 + r;
        atomicAdd(&out[row*32 + m],      a0[r] + bias0);
        atomicAdd(&out[row*32 + 16 + m], a1[r] + bias1);
    }
}

extern "C" void kernel_launch(void* const* d_in, const int* in_sizes, int n_in,
                              void* d_out, int out_size, void* d_ws, size_t ws_size,
                              hipStream_t stream)
{
    const float* O    = (const float*)d_in[0];
    const float* Wenc = (const float*)d_in[1];
    const float* benc = (const float*)d_in[2];
    const float* W1   = (const float*)d_in[3];
    const float* b1   = (const float*)d_in[4];
    const float* W2   = (const float*)d_in[5];
    const float* b2   = (const float*)d_in[6];
    const float* W3   = (const float*)d_in[7];
    const float* b3   = (const float*)d_in[8];
    const float* W4   = (const float*)d_in[9];
    const float* b4   = (const float*)d_in[10];
    const float* Wdec = (const float*)d_in[11];
    const float* bdec = (const float*)d_in[12];
    float* out = (float*)d_out;
    unsigned short* ws = (unsigned short*)d_ws;

    hipMemsetAsync(d_out, 0, (size_t)out_size * sizeof(float), stream);
    prep_kernel<<<672, 256, 0, stream>>>(Wenc, W1, W2, W3, W4, Wdec, ws);
    fused_kernel<<<BATCHN, 256, 0, stream>>>(O, ws + OFF_WENC/2, ws + OFF_WCAT/2,
                                             benc, b1, b2, b3, b4, ws + OFF_H4/2);
    dec_kernel<<<1024, 256, 0, stream>>>(ws + OFF_H4/2, ws + OFF_WDEC/2, bdec, out);
}